// Round 4
// baseline (346.772 us; speedup 1.0000x reference)
//
#include <hip/hip_runtime.h>

#define B_ 2
#define S_ 2048
#define D_ 1024
#define H_ 16
#define DK_ 64

typedef __attribute__((ext_vector_type(8))) short vshort8;   // 8 x bf16 (4 VGPRs)
typedef __attribute__((ext_vector_type(4))) float vfloat4;   // MFMA C/D

// f32 -> bf16 round-to-nearest-even
static __device__ inline unsigned short f2bf(float f) {
    unsigned int x = __float_as_uint(f);
    x += 0x7fffu + ((x >> 16) & 1u);
    return (unsigned short)(x >> 16);
}
// f32 -> bf16 round-half-up (2 VALU ops; fine inside softmax, P in [0,1])
static __device__ inline unsigned short f2bf_fast(float f) {
    return (unsigned short)((__float_as_uint(f) + 0x8000u) >> 16);
}
static __device__ inline float bf2f(unsigned short u) {
    return __uint_as_float((unsigned int)u << 16);
}

// async global->LDS, 16 B per lane (m97 pattern)
typedef __attribute__((address_space(1))) const unsigned int as1_uint;
typedef __attribute__((address_space(3))) unsigned int as3_uint;
static __device__ inline void async16(const void* g, void* l) {
    __builtin_amdgcn_global_load_lds((as1_uint*)g, (as3_uint*)l, 16, 0, 0);
}

// ---------------------------------------------------------------------------
// Cast up to 4 f32 tensors to bf16.
// ---------------------------------------------------------------------------
__global__ __launch_bounds__(256) void cast_bf16_kernel(
    const float* s0, const float* s1, const float* s2, const float* s3,
    unsigned short* d0, unsigned short* d1, unsigned short* d2, unsigned short* d3)
{
    int z = blockIdx.z;
    const float* s = (z == 0) ? s0 : (z == 1) ? s1 : (z == 2) ? s2 : s3;
    unsigned short* d = (z == 0) ? d0 : (z == 1) ? d1 : (z == 2) ? d2 : d3;
    int i = (blockIdx.x * 256 + threadIdx.x) * 8;
    float4 f0 = *(const float4*)(s + i);
    float4 f1 = *(const float4*)(s + i + 4);
    uint4 o;
    o.x = (unsigned int)f2bf(f0.x) | ((unsigned int)f2bf(f0.y) << 16);
    o.y = (unsigned int)f2bf(f0.z) | ((unsigned int)f2bf(f0.w) << 16);
    o.z = (unsigned int)f2bf(f1.x) | ((unsigned int)f2bf(f1.y) << 16);
    o.w = (unsigned int)f2bf(f1.z) | ((unsigned int)f2bf(f1.w) << 16);
    *(uint4*)(d + i) = o;
}

// ---------------------------------------------------------------------------
// GEMM: out[M][N] = A[M][K] @ W[N][K]^T + bias. M=4096, N=K=1024 hardcoded.
// (unchanged from R3: async16 staging, XOR swizzle, QKV fused via blockIdx.z)
// ---------------------------------------------------------------------------
__global__ __launch_bounds__(256) void gemm_bt_kernel(
    const unsigned short* __restrict__ A0, const unsigned short* __restrict__ A1, const unsigned short* __restrict__ A2,
    const unsigned short* __restrict__ W0, const unsigned short* __restrict__ W1, const unsigned short* __restrict__ W2,
    const float* __restrict__ bb0, const float* __restrict__ bb1, const float* __restrict__ bb2,
    unsigned short* __restrict__ o0, unsigned short* __restrict__ o1, unsigned short* __restrict__ o2,
    float* __restrict__ of, int f32out)
{
    __shared__ unsigned short As[128][32];
    __shared__ unsigned short Ws[128][32];

    const int z = blockIdx.z;
    const unsigned short* A    = (z == 0) ? A0 : (z == 1) ? A1 : A2;
    const unsigned short* Wt   = (z == 0) ? W0 : (z == 1) ? W1 : W2;
    const float* bias          = (z == 0) ? bb0 : (z == 1) ? bb1 : bb2;
    unsigned short* outb       = (z == 0) ? o0 : (z == 1) ? o1 : o2;

    const int tid  = threadIdx.x;
    const int wave = tid >> 6;
    const int lane = tid & 63;
    const int l15  = lane & 15;
    const int quad = lane >> 4;
    const int wm   = wave >> 1;
    const int wn   = wave & 1;
    const int m0   = blockIdx.y * 128;
    const int n0   = blockIdx.x * 128;

    const int li  = lane >> 2;
    const int lj  = lane & 3;
    const int lcc = (lj ^ ((li >> 1) & 3)) * 8;
    const int c0  = wave * 2;

    const unsigned short* gA0 = A  + (long)(m0 + c0 * 16      + li) * D_ + lcc;
    const unsigned short* gA1 = A  + (long)(m0 + c0 * 16 + 16 + li) * D_ + lcc;
    const unsigned short* gW0 = Wt + (long)(n0 + c0 * 16      + li) * D_ + lcc;
    const unsigned short* gW1 = Wt + (long)(n0 + c0 * 16 + 16 + li) * D_ + lcc;
    unsigned short* lA0 = (unsigned short*)As + (c0    ) * 512 + lane * 8;
    unsigned short* lA1 = (unsigned short*)As + (c0 + 1) * 512 + lane * 8;
    unsigned short* lW0 = (unsigned short*)Ws + (c0    ) * 512 + lane * 8;
    unsigned short* lW1 = (unsigned short*)Ws + (c0 + 1) * 512 + lane * 8;

    vfloat4 acc[4][4];
    for (int rt = 0; rt < 4; rt++)
        for (int ct = 0; ct < 4; ct++) {
            vfloat4 zz = {0.f, 0.f, 0.f, 0.f};
            acc[rt][ct] = zz;
        }

    const int sw = (quad ^ ((l15 >> 1) & 3)) * 8;

    for (int k0 = 0; k0 < 1024; k0 += 32) {
        async16(gA0 + k0, lA0);
        async16(gA1 + k0, lA1);
        async16(gW0 + k0, lW0);
        async16(gW1 + k0, lW1);
        __syncthreads();

        vshort8 af[4], bf[4];
        for (int rt = 0; rt < 4; rt++)
            af[rt] = *(const vshort8*)&As[wm * 64 + rt * 16 + l15][sw];
        for (int ct = 0; ct < 4; ct++)
            bf[ct] = *(const vshort8*)&Ws[wn * 64 + ct * 16 + l15][sw];
        for (int rt = 0; rt < 4; rt++)
            for (int ct = 0; ct < 4; ct++)
                acc[rt][ct] = __builtin_amdgcn_mfma_f32_16x16x32_bf16(af[rt], bf[ct], acc[rt][ct], 0, 0, 0);
        __syncthreads();
    }

    for (int rt = 0; rt < 4; rt++) {
        int row = m0 + wm * 64 + rt * 16 + quad * 4;
        for (int ct = 0; ct < 4; ct++) {
            int col = n0 + wn * 64 + ct * 16 + l15;
            float bvv = bias[col];
            if (f32out) {
                for (int r = 0; r < 4; r++)
                    of[(long)(row + r) * D_ + col] = acc[rt][ct][r] + bvv;
            } else {
                for (int r = 0; r < 4; r++)
                    outb[(long)(row + r) * D_ + col] = f2bf(acc[rt][ct][r] + bvv);
            }
        }
    }
}

// ---------------------------------------------------------------------------
// RMSNorm + RoPE + (B,S,D)->(B,H,S,DK) relayout, bf16 in/out.
// blockIdx.y: 0 = Q (norm+rope, * 0.125*log2(e) so attn can use exp2), 1 = K.
// ---------------------------------------------------------------------------
__global__ __launch_bounds__(256) void normrope_kernel(
    const unsigned short* __restrict__ xq, const unsigned short* __restrict__ xk,
    const float* __restrict__ cosb, const float* __restrict__ sinb,
    const float* __restrict__ qw, const float* __restrict__ kw,
    unsigned short* __restrict__ Qn, unsigned short* __restrict__ Kn)
{
    int mode = blockIdx.y;
    const unsigned short* x = mode ? xk : xq;
    const float* w          = mode ? kw : qw;
    unsigned short* out     = mode ? Kn : Qn;

    int wave = threadIdx.x >> 6;
    int lane = threadIdx.x & 63;
    int g = blockIdx.x * 4 + wave;
    int i = g >> 4;
    int h = g & 15;
    int s = i & (S_ - 1);
    int b = i >> 11;

    float v = bf2f(x[(long)i * D_ + h * DK_ + lane]);
    float ss = v * v;
    for (int off = 1; off < 64; off <<= 1) ss += __shfl_xor(ss, off, 64);
    float rn = rsqrtf(ss * (1.0f / 64.0f) + 1e-6f);
    float xn = v * rn * w[lane];
    float other = __shfl_xor(xn, 32, 64);
    float rot = (lane < 32) ? -other : other;
    float val = xn * cosb[s * DK_ + lane] + rot * sinb[s * DK_ + lane];
    if (mode == 0) val *= 0.18033688011112042f;   // (1/8) * log2(e)
    out[((long)(b * H_ + h) * S_ + s) * DK_ + lane] = f2bf(val);
}

// ---------------------------------------------------------------------------
// V relayout: (B,S,D) bf16 -> (B,H,DK,S) bf16 via LDS tile.
// ---------------------------------------------------------------------------
__global__ __launch_bounds__(256) void transpose_v_kernel(
    const unsigned short* __restrict__ X,
    unsigned short* __restrict__ Vt)
{
    __shared__ unsigned short T[64][72];
    int st = blockIdx.x, bh = blockIdx.y;
    int b = bh >> 4, h = bh & 15;
    int s0 = st * 64;

    for (int it = 0; it < 2; it++) {
        int idx = threadIdx.x + it * 256;
        int r = idx >> 3;
        int c = (idx & 7) * 8;
        *(uint4*)&T[r][c] = *(const uint4*)&X[(long)(b * S_ + s0 + r) * D_ + h * 64 + c];
    }
    __syncthreads();
    for (int it = 0; it < 2; it++) {
        int idx = threadIdx.x + it * 256;
        int dk = idx >> 3;
        int ss = (idx & 7) * 8;
        unsigned short pk[8];
        for (int j = 0; j < 8; j++) pk[j] = T[ss + j][dk];
        *(uint4*)&Vt[((long)(b * H_ + h) * DK_ + dk) * S_ + s0 + ss] = *(uint4*)pk;
    }
}

// ---------------------------------------------------------------------------
// Causal flash attention, barrier-free.
// Each wave owns 32 q rows (2 x 16) of one (b,h); K/V fragments are loaded
// directly global->VGPR (L2-resident); the only LDS use is a PER-WAVE scratch
// for the P C-layout -> A/B-operand transpose (no __syncthreads anywhere).
// Q pre-scaled by (1/8)*log2(e) so softmax uses exp2f (raw v_exp_f32).
// Grid (16 strip-groups, 32 bh), heavy-first: sg = 15 - blockIdx.x.
// Wave w handles q rows [sg*128 + w*32, +32); kv tiles 0 .. 2sg + (w>>1).
// Diagonal masking is needed only on each wave's LAST kv tile.
// ---------------------------------------------------------------------------
__global__ __launch_bounds__(256, 2) void attn_kernel(
    const unsigned short* __restrict__ Q,   // (B*H, S, DK) bf16, pre-scaled
    const unsigned short* __restrict__ K,   // (B*H, S, DK) bf16
    const unsigned short* __restrict__ Vt,  // (B*H, DK, S) bf16
    unsigned short* __restrict__ O)         // (B, S, D) bf16
{
    __shared__ unsigned short Pall[4][32][72];   // per-wave private P scratch

    const int tid  = threadIdx.x;
    const int wave = tid >> 6;
    const int lane = tid & 63;
    const int l15  = lane & 15;
    const int quad = lane >> 4;
    const int sg   = (gridDim.x - 1) - blockIdx.x;
    const int bh   = blockIdx.y;
    const int b    = bh >> 4;
    const int h    = bh & 15;
    const int q0   = sg * 128 + wave * 32;
    const long baseQ = (long)bh * S_ * DK_;
    const long baseV = (long)bh * DK_ * S_;

    unsigned short (* __restrict__ Pw)[72] = Pall[wave];

    // Q fragments: B-operand rows q, k = kh*32+quad*8
    vshort8 bq[2][2];
    for (int nq = 0; nq < 2; nq++)
        for (int kh = 0; kh < 2; kh++)
            bq[nq][kh] = *(const vshort8*)&Q[baseQ + (long)(q0 + nq * 16 + l15) * DK_ + kh * 32 + quad * 8];

    vfloat4 Oacc[4][2];
    for (int dt = 0; dt < 4; dt++)
        for (int nq = 0; nq < 2; nq++) { vfloat4 zz = {0.f,0.f,0.f,0.f}; Oacc[dt][nq] = zz; }
    float m_run[2] = {-1e30f, -1e30f};
    float l_run[2] = {0.f, 0.f};

    const int nkt = 2 * sg + 1 + (wave >> 1);
    for (int kt = 0; kt < nkt; kt++) {
        const int k0 = kt * 64;

        // K fragments (A-operand): rows kv = ct*16+l15, k = kh*32+quad*8
        vshort8 ak[4][2];
        for (int ct = 0; ct < 4; ct++)
            for (int kh = 0; kh < 2; kh++)
                ak[ct][kh] = *(const vshort8*)&K[baseQ + (long)(k0 + ct * 16 + l15) * DK_ + kh * 32 + quad * 8];

        // S^T = K Q^T : C-layout col=q=l15, row=kv=quad*4+r (per ct tile)
        vfloat4 sc[2][4];
        for (int nq = 0; nq < 2; nq++)
            for (int ct = 0; ct < 4; ct++) {
                vfloat4 a = {0.f, 0.f, 0.f, 0.f};
                a = __builtin_amdgcn_mfma_f32_16x16x32_bf16(ak[ct][0], bq[nq][0], a, 0, 0, 0);
                a = __builtin_amdgcn_mfma_f32_16x16x32_bf16(ak[ct][1], bq[nq][1], a, 0, 0, 0);
                sc[nq][ct] = a;
            }

        // V^T fragments (A-operand for PV): rows dk = dt*16+l15, k over kv
        // issued here so the L2 latency overlaps the softmax VALU below
        vshort8 av[4][2];
        for (int dt = 0; dt < 4; dt++)
            for (int kh = 0; kh < 2; kh++)
                av[dt][kh] = *(const vshort8*)&Vt[baseV + (long)(dt * 16 + l15) * S_ + k0 + kh * 32 + quad * 8];

        if (kt == nkt - 1) {   // causal mask, last tile only
            for (int nq = 0; nq < 2; nq++) {
                int qg = q0 + nq * 16 + l15;
                for (int ct = 0; ct < 4; ct++) {
                    int kvb = k0 + ct * 16 + quad * 4;
                    for (int r = 0; r < 4; r++)
                        if (kvb + r > qg) sc[nq][ct][r] = -1e30f;
                }
            }
        }

        // online softmax (log2 domain); lane owns q-row l15, 16 kv in-lane
        for (int nq = 0; nq < 2; nq++) {
            float mt = -1e30f;
            for (int ct = 0; ct < 4; ct++)
                for (int r = 0; r < 4; r++) mt = fmaxf(mt, sc[nq][ct][r]);
            mt = fmaxf(mt, __shfl_xor(mt, 16, 64));
            mt = fmaxf(mt, __shfl_xor(mt, 32, 64));
            float mnew  = fmaxf(m_run[nq], mt);
            float alpha = exp2f(m_run[nq] - mnew);
            m_run[nq] = mnew;
            float rs = 0.f;
            for (int ct = 0; ct < 4; ct++) {
                float p0 = exp2f(sc[nq][ct][0] - mnew);
                float p1 = exp2f(sc[nq][ct][1] - mnew);
                float p2 = exp2f(sc[nq][ct][2] - mnew);
                float p3 = exp2f(sc[nq][ct][3] - mnew);
                rs += (p0 + p1) + (p2 + p3);
                uint2 o;
                o.x = (unsigned int)f2bf_fast(p0) | ((unsigned int)f2bf_fast(p1) << 16);
                o.y = (unsigned int)f2bf_fast(p2) | ((unsigned int)f2bf_fast(p3) << 16);
                *(uint2*)&Pw[nq * 16 + l15][ct * 16 + quad * 4] = o;   // P^T
            }
            rs += __shfl_xor(rs, 16, 64);
            rs += __shfl_xor(rs, 32, 64);
            l_run[nq] = l_run[nq] * alpha + rs;
            for (int dt = 0; dt < 4; dt++)
                for (int r = 0; r < 4; r++) Oacc[dt][nq][r] *= alpha;
        }

        // P B-operand fragments (same-wave LDS round trip; lgkmcnt only)
        vshort8 bp[2][2];
        for (int nq = 0; nq < 2; nq++)
            for (int kh = 0; kh < 2; kh++)
                bp[nq][kh] = *(const vshort8*)&Pw[nq * 16 + l15][kh * 32 + quad * 8];

        // O^T += V^T P^T
        for (int dt = 0; dt < 4; dt++)
            for (int nq = 0; nq < 2; nq++) {
                Oacc[dt][nq] = __builtin_amdgcn_mfma_f32_16x16x32_bf16(av[dt][0], bp[nq][0], Oacc[dt][nq], 0, 0, 0);
                Oacc[dt][nq] = __builtin_amdgcn_mfma_f32_16x16x32_bf16(av[dt][1], bp[nq][1], Oacc[dt][nq], 0, 0, 0);
            }
    }

    // epilogue: lane holds col q=l15 (per nq), rows dk = dt*16+quad*4+r
    for (int nq = 0; nq < 2; nq++) {
        float inv = 1.0f / l_run[nq];
        int qg = q0 + nq * 16 + l15;
        long rowbase = (long)(b * S_ + qg) * D_ + h * 64;
        for (int dt = 0; dt < 4; dt++) {
            unsigned short pk[4];
            for (int r = 0; r < 4; r++) pk[r] = f2bf(Oacc[dt][nq][r] * inv);
            uint2 o;
            o.x = (unsigned int)pk[0] | ((unsigned int)pk[1] << 16);
            o.y = (unsigned int)pk[2] | ((unsigned int)pk[3] << 16);
            *(uint2*)&O[rowbase + dt * 16 + quad * 4] = o;
        }
    }
}

// ---------------------------------------------------------------------------
extern "C" void kernel_launch(void* const* d_in, const int* in_sizes, int n_in,
                              void* d_out, int out_size, void* d_ws, size_t ws_size,
                              hipStream_t stream) {
    const float* q    = (const float*)d_in[0];
    const float* k    = (const float*)d_in[1];
    const float* v    = (const float*)d_in[2];
    const float* cosb = (const float*)d_in[4];
    const float* sinb = (const float*)d_in[5];
    const float* wq   = (const float*)d_in[6];
    const float* bq   = (const float*)d_in[7];
    const float* wk   = (const float*)d_in[8];
    const float* bk   = (const float*)d_in[9];
    const float* wv   = (const float*)d_in[10];
    const float* bv   = (const float*)d_in[11];
    const float* wo   = (const float*)d_in[12];
    const float* bo   = (const float*)d_in[13];
    const float* qn_w = (const float*)d_in[14];
    const float* kn_w = (const float*)d_in[15];

    const long MB = 1024 * 1024;
    char* ws = (char*)d_ws;
    unsigned short* xq   = (unsigned short*)(ws + 0 * MB);
    unsigned short* xk   = (unsigned short*)(ws + 8 * MB);
    unsigned short* xv   = (unsigned short*)(ws + 16 * MB);
    unsigned short* wqb  = (unsigned short*)(ws + 24 * MB);
    unsigned short* wkb  = (unsigned short*)(ws + 26 * MB);
    unsigned short* wvb  = (unsigned short*)(ws + 28 * MB);
    unsigned short* wob  = (unsigned short*)(ws + 30 * MB);
    unsigned short* tmpq = (unsigned short*)(ws + 32 * MB);
    unsigned short* tmpk = (unsigned short*)(ws + 40 * MB);
    unsigned short* tmpv = (unsigned short*)(ws + 48 * MB);
    unsigned short* Qn   = (unsigned short*)(ws + 0 * MB);
    unsigned short* Kn   = (unsigned short*)(ws + 8 * MB);
    unsigned short* Vtb  = (unsigned short*)(ws + 16 * MB);
    unsigned short* Ob   = (unsigned short*)(ws + 32 * MB);

    dim3 blk(256);
    cast_bf16_kernel<<<dim3(2048, 1, 3), blk, 0, stream>>>(q, k, v, q, xq, xk, xv, xq);
    cast_bf16_kernel<<<dim3(512, 1, 4), blk, 0, stream>>>(wq, wk, wv, wo, wqb, wkb, wvb, wob);

    // fused QKV projection: 768 blocks = 3 blocks/CU
    gemm_bt_kernel<<<dim3(8, 32, 3), blk, 0, stream>>>(
        xq, xk, xv, wqb, wkb, wvb, bq, bk, bv, tmpq, tmpk, tmpv, nullptr, 0);

    normrope_kernel<<<dim3(16384, 2), blk, 0, stream>>>(
        tmpq, tmpk, cosb, sinb, qn_w, kn_w, Qn, Kn);
    transpose_v_kernel<<<dim3(32, 32), blk, 0, stream>>>(tmpv, Vtb);

    attn_kernel<<<dim3(16, 32), blk, 0, stream>>>(Qn, Kn, Vtb, Ob);

    // output projection, f32 out
    gemm_bt_kernel<<<dim3(8, 32, 1), blk, 0, stream>>>(
        Ob, Ob, Ob, wob, wob, wob, bo, bo, bo, nullptr, nullptr, nullptr,
        (float*)d_out, 1);
}

// Round 5
// 280.177 us; speedup vs baseline: 1.2377x; 1.2377x over previous
//
#include <hip/hip_runtime.h>

#define B_ 2
#define S_ 2048
#define D_ 1024
#define H_ 16
#define DK_ 64

typedef __attribute__((ext_vector_type(8))) short vshort8;   // 8 x bf16 (4 VGPRs)
typedef __attribute__((ext_vector_type(4))) float vfloat4;   // MFMA C/D

// f32 -> bf16 round-to-nearest-even
static __device__ inline unsigned short f2bf(float f) {
    unsigned int x = __float_as_uint(f);
    x += 0x7fffu + ((x >> 16) & 1u);
    return (unsigned short)(x >> 16);
}
// f32 -> bf16 round-half-up (2 VALU ops; fine inside softmax, P in [0,1])
static __device__ inline unsigned short f2bf_fast(float f) {
    return (unsigned short)((__float_as_uint(f) + 0x8000u) >> 16);
}
static __device__ inline float bf2f(unsigned short u) {
    return __uint_as_float((unsigned int)u << 16);
}

// async global->LDS, 16 B per lane (m97 pattern)
typedef __attribute__((address_space(1))) const unsigned int as1_uint;
typedef __attribute__((address_space(3))) unsigned int as3_uint;
static __device__ inline void async16(const void* g, void* l) {
    __builtin_amdgcn_global_load_lds((as1_uint*)g, (as3_uint*)l, 16, 0, 0);
}

// ---------------------------------------------------------------------------
// Cast up to 4 f32 tensors to bf16.
// ---------------------------------------------------------------------------
__global__ __launch_bounds__(256) void cast_bf16_kernel(
    const float* s0, const float* s1, const float* s2, const float* s3,
    unsigned short* d0, unsigned short* d1, unsigned short* d2, unsigned short* d3)
{
    int z = blockIdx.z;
    const float* s = (z == 0) ? s0 : (z == 1) ? s1 : (z == 2) ? s2 : s3;
    unsigned short* d = (z == 0) ? d0 : (z == 1) ? d1 : (z == 2) ? d2 : d3;
    int i = (blockIdx.x * 256 + threadIdx.x) * 8;
    float4 f0 = *(const float4*)(s + i);
    float4 f1 = *(const float4*)(s + i + 4);
    uint4 o;
    o.x = (unsigned int)f2bf(f0.x) | ((unsigned int)f2bf(f0.y) << 16);
    o.y = (unsigned int)f2bf(f0.z) | ((unsigned int)f2bf(f0.w) << 16);
    o.z = (unsigned int)f2bf(f1.x) | ((unsigned int)f2bf(f1.y) << 16);
    o.w = (unsigned int)f2bf(f1.z) | ((unsigned int)f2bf(f1.w) << 16);
    *(uint4*)(d + i) = o;
}

// ---------------------------------------------------------------------------
// GEMM: out[M][N] = A[M][K] @ W[N][K]^T + bias. M=4096, N=K=1024 hardcoded.
// (async16 staging, XOR swizzle, QKV fused via blockIdx.z)
// ---------------------------------------------------------------------------
__global__ __launch_bounds__(256) void gemm_bt_kernel(
    const unsigned short* __restrict__ A0, const unsigned short* __restrict__ A1, const unsigned short* __restrict__ A2,
    const unsigned short* __restrict__ W0, const unsigned short* __restrict__ W1, const unsigned short* __restrict__ W2,
    const float* __restrict__ bb0, const float* __restrict__ bb1, const float* __restrict__ bb2,
    unsigned short* __restrict__ o0, unsigned short* __restrict__ o1, unsigned short* __restrict__ o2,
    float* __restrict__ of, int f32out)
{
    __shared__ unsigned short As[128][32];
    __shared__ unsigned short Ws[128][32];

    const int z = blockIdx.z;
    const unsigned short* A    = (z == 0) ? A0 : (z == 1) ? A1 : A2;
    const unsigned short* Wt   = (z == 0) ? W0 : (z == 1) ? W1 : W2;
    const float* bias          = (z == 0) ? bb0 : (z == 1) ? bb1 : bb2;
    unsigned short* outb       = (z == 0) ? o0 : (z == 1) ? o1 : o2;

    const int tid  = threadIdx.x;
    const int wave = tid >> 6;
    const int lane = tid & 63;
    const int l15  = lane & 15;
    const int quad = lane >> 4;
    const int wm   = wave >> 1;
    const int wn   = wave & 1;
    const int m0   = blockIdx.y * 128;
    const int n0   = blockIdx.x * 128;

    const int li  = lane >> 2;
    const int lj  = lane & 3;
    const int lcc = (lj ^ ((li >> 1) & 3)) * 8;
    const int c0  = wave * 2;

    const unsigned short* gA0 = A  + (long)(m0 + c0 * 16      + li) * D_ + lcc;
    const unsigned short* gA1 = A  + (long)(m0 + c0 * 16 + 16 + li) * D_ + lcc;
    const unsigned short* gW0 = Wt + (long)(n0 + c0 * 16      + li) * D_ + lcc;
    const unsigned short* gW1 = Wt + (long)(n0 + c0 * 16 + 16 + li) * D_ + lcc;
    unsigned short* lA0 = (unsigned short*)As + (c0    ) * 512 + lane * 8;
    unsigned short* lA1 = (unsigned short*)As + (c0 + 1) * 512 + lane * 8;
    unsigned short* lW0 = (unsigned short*)Ws + (c0    ) * 512 + lane * 8;
    unsigned short* lW1 = (unsigned short*)Ws + (c0 + 1) * 512 + lane * 8;

    vfloat4 acc[4][4];
    for (int rt = 0; rt < 4; rt++)
        for (int ct = 0; ct < 4; ct++) {
            vfloat4 zz = {0.f, 0.f, 0.f, 0.f};
            acc[rt][ct] = zz;
        }

    const int sw = (quad ^ ((l15 >> 1) & 3)) * 8;

    for (int k0 = 0; k0 < 1024; k0 += 32) {
        async16(gA0 + k0, lA0);
        async16(gA1 + k0, lA1);
        async16(gW0 + k0, lW0);
        async16(gW1 + k0, lW1);
        __syncthreads();

        vshort8 af[4], bf[4];
        for (int rt = 0; rt < 4; rt++)
            af[rt] = *(const vshort8*)&As[wm * 64 + rt * 16 + l15][sw];
        for (int ct = 0; ct < 4; ct++)
            bf[ct] = *(const vshort8*)&Ws[wn * 64 + ct * 16 + l15][sw];
        for (int rt = 0; rt < 4; rt++)
            for (int ct = 0; ct < 4; ct++)
                acc[rt][ct] = __builtin_amdgcn_mfma_f32_16x16x32_bf16(af[rt], bf[ct], acc[rt][ct], 0, 0, 0);
        __syncthreads();
    }

    for (int rt = 0; rt < 4; rt++) {
        int row = m0 + wm * 64 + rt * 16 + quad * 4;
        for (int ct = 0; ct < 4; ct++) {
            int col = n0 + wn * 64 + ct * 16 + l15;
            float bvv = bias[col];
            if (f32out) {
                for (int r = 0; r < 4; r++)
                    of[(long)(row + r) * D_ + col] = acc[rt][ct][r] + bvv;
            } else {
                for (int r = 0; r < 4; r++)
                    outb[(long)(row + r) * D_ + col] = f2bf(acc[rt][ct][r] + bvv);
            }
        }
    }
}

// ---------------------------------------------------------------------------
// RMSNorm + RoPE + (B,S,D)->(B,H,S,DK) relayout, bf16 in/out.
// blockIdx.y: 0 = Q (norm+rope, * 0.125*log2(e) so attn can use exp2), 1 = K.
// ---------------------------------------------------------------------------
__global__ __launch_bounds__(256) void normrope_kernel(
    const unsigned short* __restrict__ xq, const unsigned short* __restrict__ xk,
    const float* __restrict__ cosb, const float* __restrict__ sinb,
    const float* __restrict__ qw, const float* __restrict__ kw,
    unsigned short* __restrict__ Qn, unsigned short* __restrict__ Kn)
{
    int mode = blockIdx.y;
    const unsigned short* x = mode ? xk : xq;
    const float* w          = mode ? kw : qw;
    unsigned short* out     = mode ? Kn : Qn;

    int wave = threadIdx.x >> 6;
    int lane = threadIdx.x & 63;
    int g = blockIdx.x * 4 + wave;
    int i = g >> 4;
    int h = g & 15;
    int s = i & (S_ - 1);
    int b = i >> 11;

    float v = bf2f(x[(long)i * D_ + h * DK_ + lane]);
    float ss = v * v;
    for (int off = 1; off < 64; off <<= 1) ss += __shfl_xor(ss, off, 64);
    float rn = rsqrtf(ss * (1.0f / 64.0f) + 1e-6f);
    float xn = v * rn * w[lane];
    float other = __shfl_xor(xn, 32, 64);
    float rot = (lane < 32) ? -other : other;
    float val = xn * cosb[s * DK_ + lane] + rot * sinb[s * DK_ + lane];
    if (mode == 0) val *= 0.18033688011112042f;   // (1/8) * log2(e)
    out[((long)(b * H_ + h) * S_ + s) * DK_ + lane] = f2bf(val);
}

// ---------------------------------------------------------------------------
// V relayout: (B,S,D) bf16 -> (B,H,DK,S) bf16 via LDS tile.
// ---------------------------------------------------------------------------
__global__ __launch_bounds__(256) void transpose_v_kernel(
    const unsigned short* __restrict__ X,
    unsigned short* __restrict__ Vt)
{
    __shared__ unsigned short T[64][72];
    int st = blockIdx.x, bh = blockIdx.y;
    int b = bh >> 4, h = bh & 15;
    int s0 = st * 64;

    for (int it = 0; it < 2; it++) {
        int idx = threadIdx.x + it * 256;
        int r = idx >> 3;
        int c = (idx & 7) * 8;
        *(uint4*)&T[r][c] = *(const uint4*)&X[(long)(b * S_ + s0 + r) * D_ + h * 64 + c];
    }
    __syncthreads();
    for (int it = 0; it < 2; it++) {
        int idx = threadIdx.x + it * 256;
        int dk = idx >> 3;
        int ss = (idx & 7) * 8;
        unsigned short pk[8];
        for (int j = 0; j < 8; j++) pk[j] = T[ss + j][dk];
        *(uint4*)&Vt[((long)(b * H_ + h) * DK_ + dk) * S_ + s0 + ss] = *(uint4*)pk;
    }
}

// ---------------------------------------------------------------------------
// Causal flash attention: paired q-strips (qa, qb=31-qa) for perfect load
// balance; LDS-staged K/V shared by all 4 waves, double-buffered with async16
// prefetch and ONE barrier per kv tile. Transposed dataflow (S^T = K Q^T,
// O^T = V^T P^T); per-wave private P scratch (no barrier for P round-trip).
// Q pre-scaled by (1/8)*log2(e); softmax in exp2 domain.
// LDS tiles are unpadded [64][64] with XOR slot swizzle: LDS[r][j] holds
// global 16B-slot j^(r&7), staged by choosing the global source column.
// Grid (16, B*H). Wave owns 16 q rows of each strip.
// ---------------------------------------------------------------------------
__global__ __launch_bounds__(256, 2) void attn_kernel(
    const unsigned short* __restrict__ Q,   // (B*H, S, DK) bf16, pre-scaled
    const unsigned short* __restrict__ K,   // (B*H, S, DK) bf16
    const unsigned short* __restrict__ Vt,  // (B*H, DK, S) bf16
    unsigned short* __restrict__ O)         // (B, S, D) bf16
{
    __shared__ unsigned short Kbuf[2][64 * 64];
    __shared__ unsigned short Vbuf[2][64 * 64];
    __shared__ unsigned short Pscr[4][2][16 * 72];

    const int tid  = threadIdx.x;
    const int wave = tid >> 6;
    const int lane = tid & 63;
    const int l15  = lane & 15;
    const int quad = lane >> 4;
    const int qa   = blockIdx.x;          // 0..15
    const int qb   = 31 - qa;             // 16..31
    const int bh   = blockIdx.y;
    const int b    = bh >> 4;
    const int h    = bh & 15;
    const long baseQ = (long)bh * S_ * DK_;
    const long baseV = (long)bh * DK_ * S_;

    // ---- staging geometry: 8 chunks/tile, chunk = 8 rows x 64 cols ----
    const int rowc  = lane >> 3;                       // row within chunk
    const int slotS = ((lane & 7) ^ rowc) * 8;         // swizzled source col
    const int cA    = wave * 2, cB = wave * 2 + 1;     // this wave's chunks

    const unsigned short* gK0 = K  + baseQ + (long)(cA * 8 + rowc) * DK_ + slotS;
    const unsigned short* gK1 = K  + baseQ + (long)(cB * 8 + rowc) * DK_ + slotS;
    const unsigned short* gV0 = Vt + baseV + (long)(cA * 8 + rowc) * S_ + slotS;
    const unsigned short* gV1 = Vt + baseV + (long)(cB * 8 + rowc) * S_ + slotS;
    const int ldsOffA = cA * 512 + lane * 8;
    const int ldsOffB = cB * 512 + lane * 8;

    // ---- Q fragments (B-operand), both strips, loaded once ----
    vshort8 bqA[2], bqB[2];
    {
        int qA = qa * 64 + wave * 16 + l15;
        int qB = qb * 64 + wave * 16 + l15;
        for (int kh = 0; kh < 2; kh++) {
            bqA[kh] = *(const vshort8*)&Q[baseQ + (long)qA * DK_ + kh * 32 + quad * 8];
            bqB[kh] = *(const vshort8*)&Q[baseQ + (long)qB * DK_ + kh * 32 + quad * 8];
        }
    }

    vfloat4 OaccA[4], OaccB[4];
    for (int dt = 0; dt < 4; dt++) {
        vfloat4 zz = {0.f, 0.f, 0.f, 0.f};
        OaccA[dt] = zz; OaccB[dt] = zz;
    }
    float mA = -1e30f, lA = 0.f, mB = -1e30f, lB = 0.f;

    unsigned short* PA = &Pscr[wave][0][0];
    unsigned short* PB = &Pscr[wave][1][0];

    const int nkt = qb + 1;

    // prologue: stage tile 0 into buffer 0
    async16(gK0, &Kbuf[0][ldsOffA]);
    async16(gK1, &Kbuf[0][ldsOffB]);
    async16(gV0, &Vbuf[0][ldsOffA]);
    async16(gV1, &Vbuf[0][ldsOffB]);
    __syncthreads();

    for (int t = 0; t < nkt; t++) {
        const int cur = t & 1;
        if (t + 1 < nkt) {   // prefetch next tile into the other buffer
            const int nxt = cur ^ 1;
            const long ko = (long)(t + 1) * 64;
            async16(gK0 + ko * DK_, &Kbuf[nxt][ldsOffA]);
            async16(gK1 + ko * DK_, &Kbuf[nxt][ldsOffB]);
            async16(gV0 + ko,       &Vbuf[nxt][ldsOffA]);
            async16(gV1 + ko,       &Vbuf[nxt][ldsOffB]);
        }

        // K fragments (A-operand), shared by both strips
        vshort8 ak[4][2];
        for (int ct = 0; ct < 4; ct++)
            for (int kh = 0; kh < 2; kh++) {
                int r = ct * 16 + l15;
                int sl = (kh * 4 + quad) ^ (l15 & 7);
                ak[ct][kh] = *(const vshort8*)&Kbuf[cur][r * 64 + sl * 8];
            }
        // V^T fragments (A-operand for PV), shared by both strips
        vshort8 av[4][2];
        for (int dt = 0; dt < 4; dt++)
            for (int kh = 0; kh < 2; kh++) {
                int r = dt * 16 + l15;
                int sl = (kh * 4 + quad) ^ (l15 & 7);
                av[dt][kh] = *(const vshort8*)&Vbuf[cur][r * 64 + sl * 8];
            }

        const int k0 = t * 64;
        const bool actA = (t <= qa);

        if (actA) {   // ---- strip A ----
            vfloat4 sc[4];
            for (int ct = 0; ct < 4; ct++) {
                vfloat4 a = {0.f, 0.f, 0.f, 0.f};
                a = __builtin_amdgcn_mfma_f32_16x16x32_bf16(ak[ct][0], bqA[0], a, 0, 0, 0);
                a = __builtin_amdgcn_mfma_f32_16x16x32_bf16(ak[ct][1], bqA[1], a, 0, 0, 0);
                sc[ct] = a;
            }
            if (t == qa) {
                int qg = qa * 64 + wave * 16 + l15;
                for (int ct = 0; ct < 4; ct++) {
                    int kvb = k0 + ct * 16 + quad * 4;
                    for (int r = 0; r < 4; r++)
                        if (kvb + r > qg) sc[ct][r] = -1e30f;
                }
            }
            float mt = -1e30f;
            for (int ct = 0; ct < 4; ct++)
                for (int r = 0; r < 4; r++) mt = fmaxf(mt, sc[ct][r]);
            mt = fmaxf(mt, __shfl_xor(mt, 16, 64));
            mt = fmaxf(mt, __shfl_xor(mt, 32, 64));
            float mnew  = fmaxf(mA, mt);
            float alpha = exp2f(mA - mnew);
            mA = mnew;
            float rs = 0.f;
            for (int ct = 0; ct < 4; ct++) {
                float p0 = exp2f(sc[ct][0] - mnew);
                float p1 = exp2f(sc[ct][1] - mnew);
                float p2 = exp2f(sc[ct][2] - mnew);
                float p3 = exp2f(sc[ct][3] - mnew);
                rs += (p0 + p1) + (p2 + p3);
                uint2 o;
                o.x = (unsigned int)f2bf_fast(p0) | ((unsigned int)f2bf_fast(p1) << 16);
                o.y = (unsigned int)f2bf_fast(p2) | ((unsigned int)f2bf_fast(p3) << 16);
                *(uint2*)&PA[l15 * 72 + ct * 16 + quad * 4] = o;
            }
            rs += __shfl_xor(rs, 16, 64);
            rs += __shfl_xor(rs, 32, 64);
            lA = lA * alpha + rs;
            for (int dt = 0; dt < 4; dt++)
                for (int r = 0; r < 4; r++) OaccA[dt][r] *= alpha;
            vshort8 bp[2];
            for (int kh = 0; kh < 2; kh++)
                bp[kh] = *(const vshort8*)&PA[l15 * 72 + kh * 32 + quad * 8];
            for (int dt = 0; dt < 4; dt++) {
                OaccA[dt] = __builtin_amdgcn_mfma_f32_16x16x32_bf16(av[dt][0], bp[0], OaccA[dt], 0, 0, 0);
                OaccA[dt] = __builtin_amdgcn_mfma_f32_16x16x32_bf16(av[dt][1], bp[1], OaccA[dt], 0, 0, 0);
            }
        }

        {   // ---- strip B (always active) ----
            vfloat4 sc[4];
            for (int ct = 0; ct < 4; ct++) {
                vfloat4 a = {0.f, 0.f, 0.f, 0.f};
                a = __builtin_amdgcn_mfma_f32_16x16x32_bf16(ak[ct][0], bqB[0], a, 0, 0, 0);
                a = __builtin_amdgcn_mfma_f32_16x16x32_bf16(ak[ct][1], bqB[1], a, 0, 0, 0);
                sc[ct] = a;
            }
            if (t == nkt - 1) {
                int qg = qb * 64 + wave * 16 + l15;
                for (int ct = 0; ct < 4; ct++) {
                    int kvb = k0 + ct * 16 + quad * 4;
                    for (int r = 0; r < 4; r++)
                        if (kvb + r > qg) sc[ct][r] = -1e30f;
                }
            }
            float mt = -1e30f;
            for (int ct = 0; ct < 4; ct++)
                for (int r = 0; r < 4; r++) mt = fmaxf(mt, sc[ct][r]);
            mt = fmaxf(mt, __shfl_xor(mt, 16, 64));
            mt = fmaxf(mt, __shfl_xor(mt, 32, 64));
            float mnew  = fmaxf(mB, mt);
            float alpha = exp2f(mB - mnew);
            mB = mnew;
            float rs = 0.f;
            for (int ct = 0; ct < 4; ct++) {
                float p0 = exp2f(sc[ct][0] - mnew);
                float p1 = exp2f(sc[ct][1] - mnew);
                float p2 = exp2f(sc[ct][2] - mnew);
                float p3 = exp2f(sc[ct][3] - mnew);
                rs += (p0 + p1) + (p2 + p3);
                uint2 o;
                o.x = (unsigned int)f2bf_fast(p0) | ((unsigned int)f2bf_fast(p1) << 16);
                o.y = (unsigned int)f2bf_fast(p2) | ((unsigned int)f2bf_fast(p3) << 16);
                *(uint2*)&PB[l15 * 72 + ct * 16 + quad * 4] = o;
            }
            rs += __shfl_xor(rs, 16, 64);
            rs += __shfl_xor(rs, 32, 64);
            lB = lB * alpha + rs;
            for (int dt = 0; dt < 4; dt++)
                for (int r = 0; r < 4; r++) OaccB[dt][r] *= alpha;
            vshort8 bp[2];
            for (int kh = 0; kh < 2; kh++)
                bp[kh] = *(const vshort8*)&PB[l15 * 72 + kh * 32 + quad * 8];
            for (int dt = 0; dt < 4; dt++) {
                OaccB[dt] = __builtin_amdgcn_mfma_f32_16x16x32_bf16(av[dt][0], bp[0], OaccB[dt], 0, 0, 0);
                OaccB[dt] = __builtin_amdgcn_mfma_f32_16x16x32_bf16(av[dt][1], bp[1], OaccB[dt], 0, 0, 0);
            }
        }

        __syncthreads();   // all waves done with buf[cur]; prefetch drained
    }

    // epilogue: lane holds col q=l15, rows dk = dt*16+quad*4+r
    {
        float inv = 1.0f / lA;
        int qg = qa * 64 + wave * 16 + l15;
        long rowbase = (long)(b * S_ + qg) * D_ + h * 64;
        for (int dt = 0; dt < 4; dt++) {
            unsigned short pk[4];
            for (int r = 0; r < 4; r++) pk[r] = f2bf(OaccA[dt][r] * inv);
            uint2 o;
            o.x = (unsigned int)pk[0] | ((unsigned int)pk[1] << 16);
            o.y = (unsigned int)pk[2] | ((unsigned int)pk[3] << 16);
            *(uint2*)&O[rowbase + dt * 16 + quad * 4] = o;
        }
    }
    {
        float inv = 1.0f / lB;
        int qg = qb * 64 + wave * 16 + l15;
        long rowbase = (long)(b * S_ + qg) * D_ + h * 64;
        for (int dt = 0; dt < 4; dt++) {
            unsigned short pk[4];
            for (int r = 0; r < 4; r++) pk[r] = f2bf(OaccB[dt][r] * inv);
            uint2 o;
            o.x = (unsigned int)pk[0] | ((unsigned int)pk[1] << 16);
            o.y = (unsigned int)pk[2] | ((unsigned int)pk[3] << 16);
            *(uint2*)&O[rowbase + dt * 16 + quad * 4] = o;
        }
    }
}

// ---------------------------------------------------------------------------
extern "C" void kernel_launch(void* const* d_in, const int* in_sizes, int n_in,
                              void* d_out, int out_size, void* d_ws, size_t ws_size,
                              hipStream_t stream) {
    const float* q    = (const float*)d_in[0];
    const float* k    = (const float*)d_in[1];
    const float* v    = (const float*)d_in[2];
    const float* cosb = (const float*)d_in[4];
    const float* sinb = (const float*)d_in[5];
    const float* wq   = (const float*)d_in[6];
    const float* bq   = (const float*)d_in[7];
    const float* wk   = (const float*)d_in[8];
    const float* bk   = (const float*)d_in[9];
    const float* wv   = (const float*)d_in[10];
    const float* bv   = (const float*)d_in[11];
    const float* wo   = (const float*)d_in[12];
    const float* bo   = (const float*)d_in[13];
    const float* qn_w = (const float*)d_in[14];
    const float* kn_w = (const float*)d_in[15];

    const long MB = 1024 * 1024;
    char* ws = (char*)d_ws;
    unsigned short* xq   = (unsigned short*)(ws + 0 * MB);
    unsigned short* xk   = (unsigned short*)(ws + 8 * MB);
    unsigned short* xv   = (unsigned short*)(ws + 16 * MB);
    unsigned short* wqb  = (unsigned short*)(ws + 24 * MB);
    unsigned short* wkb  = (unsigned short*)(ws + 26 * MB);
    unsigned short* wvb  = (unsigned short*)(ws + 28 * MB);
    unsigned short* wob  = (unsigned short*)(ws + 30 * MB);
    unsigned short* tmpq = (unsigned short*)(ws + 32 * MB);
    unsigned short* tmpk = (unsigned short*)(ws + 40 * MB);
    unsigned short* tmpv = (unsigned short*)(ws + 48 * MB);
    unsigned short* Qn   = (unsigned short*)(ws + 0 * MB);
    unsigned short* Kn   = (unsigned short*)(ws + 8 * MB);
    unsigned short* Vtb  = (unsigned short*)(ws + 16 * MB);
    unsigned short* Ob   = (unsigned short*)(ws + 32 * MB);

    dim3 blk(256);
    cast_bf16_kernel<<<dim3(2048, 1, 3), blk, 0, stream>>>(q, k, v, q, xq, xk, xv, xq);
    cast_bf16_kernel<<<dim3(512, 1, 4), blk, 0, stream>>>(wq, wk, wv, wo, wqb, wkb, wvb, wob);

    // fused QKV projection: 768 blocks = 3 blocks/CU
    gemm_bt_kernel<<<dim3(8, 32, 3), blk, 0, stream>>>(
        xq, xk, xv, wqb, wkb, wvb, bq, bk, bv, tmpq, tmpk, tmpv, nullptr, 0);

    normrope_kernel<<<dim3(16384, 2), blk, 0, stream>>>(
        tmpq, tmpk, cosb, sinb, qn_w, kn_w, Qn, Kn);
    transpose_v_kernel<<<dim3(32, 32), blk, 0, stream>>>(tmpv, Vtb);

    attn_kernel<<<dim3(16, 32), blk, 0, stream>>>(Qn, Kn, Vtb, Ob);

    // output projection, f32 out
    gemm_bt_kernel<<<dim3(8, 32, 1), blk, 0, stream>>>(
        Ob, Ob, Ob, wob, wob, wob, bo, bo, bo, nullptr, nullptr, nullptr,
        (float*)d_out, 1);
}

// Round 6
// 271.329 us; speedup vs baseline: 1.2780x; 1.0326x over previous
//
#include <hip/hip_runtime.h>

#define B_ 2
#define S_ 2048
#define D_ 1024
#define H_ 16
#define DK_ 64

typedef __attribute__((ext_vector_type(8))) short vshort8;   // 8 x bf16 (4 VGPRs)
typedef __attribute__((ext_vector_type(4))) float vfloat4;   // MFMA C/D

// f32 -> bf16 round-to-nearest-even
static __device__ inline unsigned short f2bf(float f) {
    unsigned int x = __float_as_uint(f);
    x += 0x7fffu + ((x >> 16) & 1u);
    return (unsigned short)(x >> 16);
}
// f32 -> bf16 round-half-up (2 VALU ops; fine inside softmax, P in [0,1])
static __device__ inline unsigned short f2bf_fast(float f) {
    return (unsigned short)((__float_as_uint(f) + 0x8000u) >> 16);
}
static __device__ inline float bf2f(unsigned short u) {
    return __uint_as_float((unsigned int)u << 16);
}

// async global->LDS, 16 B per lane (m97 pattern)
typedef __attribute__((address_space(1))) const unsigned int as1_uint;
typedef __attribute__((address_space(3))) unsigned int as3_uint;
static __device__ inline void async16(const void* g, void* l) {
    __builtin_amdgcn_global_load_lds((as1_uint*)g, (as3_uint*)l, 16, 0, 0);
}

// ---------------------------------------------------------------------------
// Cast up to 4 f32 tensors to bf16.
// ---------------------------------------------------------------------------
__global__ __launch_bounds__(256) void cast_bf16_kernel(
    const float* s0, const float* s1, const float* s2, const float* s3,
    unsigned short* d0, unsigned short* d1, unsigned short* d2, unsigned short* d3)
{
    int z = blockIdx.z;
    const float* s = (z == 0) ? s0 : (z == 1) ? s1 : (z == 2) ? s2 : s3;
    unsigned short* d = (z == 0) ? d0 : (z == 1) ? d1 : (z == 2) ? d2 : d3;
    int i = (blockIdx.x * 256 + threadIdx.x) * 8;
    float4 f0 = *(const float4*)(s + i);
    float4 f1 = *(const float4*)(s + i + 4);
    uint4 o;
    o.x = (unsigned int)f2bf(f0.x) | ((unsigned int)f2bf(f0.y) << 16);
    o.y = (unsigned int)f2bf(f0.z) | ((unsigned int)f2bf(f0.w) << 16);
    o.z = (unsigned int)f2bf(f1.x) | ((unsigned int)f2bf(f1.y) << 16);
    o.w = (unsigned int)f2bf(f1.z) | ((unsigned int)f2bf(f1.w) << 16);
    *(uint4*)(d + i) = o;
}

// ---------------------------------------------------------------------------
// GEMM: out[M][N] = A[M][K] @ W[N][K]^T + bias. M=4096, N=K=1024 hardcoded.
// async16 staging + XOR swizzle; QKV fused via blockIdx.z.
// mode 0: f32 row-major out (O-projection; uses slot-0 pointers).
// mode 1: QKV. z=0: RMSNorm+RoPE epilogue, *0.125*log2(e), -> o0 (B,H,S,DK).
//              z=1: RMSNorm+RoPE epilogue               -> o1 (B,H,S,DK).
//              z=2: plain bf16 row-major                -> o2 (B*S, D).
// Epilogue normrope: wave's 64-col tile is one head (h = 2*bx + wn); the 64 dk
// of a (row,head) are acc[rt][ct][r] over ct x 16 lanes of one quad ->
// 3 in-lane adds + 4 intra-quad shuffles for the mean; RoPE pairs are in-lane
// (ct <-> ct+2).
// ---------------------------------------------------------------------------
__global__ __launch_bounds__(256) void gemm_bt_kernel(
    const unsigned short* __restrict__ A0, const unsigned short* __restrict__ A1, const unsigned short* __restrict__ A2,
    const unsigned short* __restrict__ W0, const unsigned short* __restrict__ W1, const unsigned short* __restrict__ W2,
    const float* __restrict__ bb0, const float* __restrict__ bb1, const float* __restrict__ bb2,
    unsigned short* __restrict__ o0, unsigned short* __restrict__ o1, unsigned short* __restrict__ o2,
    float* __restrict__ of,
    const float* __restrict__ nw0, const float* __restrict__ nw1,
    const float* __restrict__ cosb, const float* __restrict__ sinb,
    int mode)
{
    __shared__ unsigned short As[128][32];
    __shared__ unsigned short Ws[128][32];

    const int z = blockIdx.z;
    const unsigned short* A    = (z == 0) ? A0 : (z == 1) ? A1 : A2;
    const unsigned short* Wt   = (z == 0) ? W0 : (z == 1) ? W1 : W2;
    const float* bias          = (z == 0) ? bb0 : (z == 1) ? bb1 : bb2;

    const int tid  = threadIdx.x;
    const int wave = tid >> 6;
    const int lane = tid & 63;
    const int l15  = lane & 15;
    const int quad = lane >> 4;
    const int wm   = wave >> 1;
    const int wn   = wave & 1;
    const int m0   = blockIdx.y * 128;
    const int n0   = blockIdx.x * 128;

    const int li  = lane >> 2;
    const int lj  = lane & 3;
    const int lcc = (lj ^ ((li >> 1) & 3)) * 8;
    const int c0  = wave * 2;

    const unsigned short* gA0 = A  + (long)(m0 + c0 * 16      + li) * D_ + lcc;
    const unsigned short* gA1 = A  + (long)(m0 + c0 * 16 + 16 + li) * D_ + lcc;
    const unsigned short* gW0 = Wt + (long)(n0 + c0 * 16      + li) * D_ + lcc;
    const unsigned short* gW1 = Wt + (long)(n0 + c0 * 16 + 16 + li) * D_ + lcc;
    unsigned short* lA0 = (unsigned short*)As + (c0    ) * 512 + lane * 8;
    unsigned short* lA1 = (unsigned short*)As + (c0 + 1) * 512 + lane * 8;
    unsigned short* lW0 = (unsigned short*)Ws + (c0    ) * 512 + lane * 8;
    unsigned short* lW1 = (unsigned short*)Ws + (c0 + 1) * 512 + lane * 8;

    vfloat4 acc[4][4];
    for (int rt = 0; rt < 4; rt++)
        for (int ct = 0; ct < 4; ct++) {
            vfloat4 zz = {0.f, 0.f, 0.f, 0.f};
            acc[rt][ct] = zz;
        }

    const int sw = (quad ^ ((l15 >> 1) & 3)) * 8;

    for (int k0 = 0; k0 < 1024; k0 += 32) {
        async16(gA0 + k0, lA0);
        async16(gA1 + k0, lA1);
        async16(gW0 + k0, lW0);
        async16(gW1 + k0, lW1);
        __syncthreads();

        vshort8 af[4], bf[4];
        for (int rt = 0; rt < 4; rt++)
            af[rt] = *(const vshort8*)&As[wm * 64 + rt * 16 + l15][sw];
        for (int ct = 0; ct < 4; ct++)
            bf[ct] = *(const vshort8*)&Ws[wn * 64 + ct * 16 + l15][sw];
        for (int rt = 0; rt < 4; rt++)
            for (int ct = 0; ct < 4; ct++)
                acc[rt][ct] = __builtin_amdgcn_mfma_f32_16x16x32_bf16(af[rt], bf[ct], acc[rt][ct], 0, 0, 0);
        __syncthreads();
    }

    if (mode == 0) {
        for (int rt = 0; rt < 4; rt++) {
            int row = m0 + wm * 64 + rt * 16 + quad * 4;
            for (int ct = 0; ct < 4; ct++) {
                int col = n0 + wn * 64 + ct * 16 + l15;
                float bvv = bias[col];
                for (int r = 0; r < 4; r++)
                    of[(long)(row + r) * D_ + col] = acc[rt][ct][r] + bvv;
            }
        }
    } else if (z == 2) {
        for (int rt = 0; rt < 4; rt++) {
            int row = m0 + wm * 64 + rt * 16 + quad * 4;
            for (int ct = 0; ct < 4; ct++) {
                int col = n0 + wn * 64 + ct * 16 + l15;
                float bvv = bias[col];
                for (int r = 0; r < 4; r++)
                    o2[(long)(row + r) * D_ + col] = f2bf(acc[rt][ct][r] + bvv);
            }
        }
    } else {
        // fused RMSNorm + RoPE epilogue for Q (z=0) / K (z=1)
        const float* w      = (z == 0) ? nw0 : nw1;
        unsigned short* out = (z == 0) ? o0  : o1;
        const float sfac    = (z == 0) ? 0.18033688011112042f : 1.0f;  // (1/8)*log2(e)
        const int h = blockIdx.x * 2 + wn;
        float wv4[4], bv4[4];
        for (int ct = 0; ct < 4; ct++) {
            int dk = ct * 16 + l15;
            wv4[ct] = w[dk];
            bv4[ct] = bias[n0 + wn * 64 + dk];
        }
        for (int rt = 0; rt < 4; rt++) {
            for (int r = 0; r < 4; r++) {
                int row = m0 + wm * 64 + rt * 16 + quad * 4 + r;   // b*S + s
                int s = row & (S_ - 1);
                int b = row >> 11;
                float x0 = acc[rt][0][r] + bv4[0];
                float x1 = acc[rt][1][r] + bv4[1];
                float x2 = acc[rt][2][r] + bv4[2];
                float x3 = acc[rt][3][r] + bv4[3];
                float ss = (x0 * x0 + x1 * x1) + (x2 * x2 + x3 * x3);
                ss += __shfl_xor(ss, 1, 64);
                ss += __shfl_xor(ss, 2, 64);
                ss += __shfl_xor(ss, 4, 64);
                ss += __shfl_xor(ss, 8, 64);
                float rn = rsqrtf(ss * (1.0f / 64.0f) + 1e-6f);
                float n0v = x0 * rn * wv4[0];
                float n1v = x1 * rn * wv4[1];
                float n2v = x2 * rn * wv4[2];
                float n3v = x3 * rn * wv4[3];
                long csb = (long)s * DK_ + l15;
                float c0v = cosb[csb], c1v = cosb[csb + 16], c2v = cosb[csb + 32], c3v = cosb[csb + 48];
                float s0v = sinb[csb], s1v = sinb[csb + 16], s2v = sinb[csb + 32], s3v = sinb[csb + 48];
                float v0 = (n0v * c0v - n2v * s0v) * sfac;
                float v1 = (n1v * c1v - n3v * s1v) * sfac;
                float v2 = (n2v * c2v + n0v * s2v) * sfac;
                float v3 = (n3v * c3v + n1v * s3v) * sfac;
                long ob = ((long)(b * H_ + h) * S_ + s) * DK_ + l15;
                out[ob]      = f2bf(v0);
                out[ob + 16] = f2bf(v1);
                out[ob + 32] = f2bf(v2);
                out[ob + 48] = f2bf(v3);
            }
        }
    }
}

// ---------------------------------------------------------------------------
// V relayout: (B,S,D) bf16 -> (B,H,DK,S) bf16 via LDS tile.
// ---------------------------------------------------------------------------
__global__ __launch_bounds__(256) void transpose_v_kernel(
    const unsigned short* __restrict__ X,
    unsigned short* __restrict__ Vt)
{
    __shared__ unsigned short T[64][72];
    int st = blockIdx.x, bh = blockIdx.y;
    int b = bh >> 4, h = bh & 15;
    int s0 = st * 64;

    for (int it = 0; it < 2; it++) {
        int idx = threadIdx.x + it * 256;
        int r = idx >> 3;
        int c = (idx & 7) * 8;
        *(uint4*)&T[r][c] = *(const uint4*)&X[(long)(b * S_ + s0 + r) * D_ + h * 64 + c];
    }
    __syncthreads();
    for (int it = 0; it < 2; it++) {
        int idx = threadIdx.x + it * 256;
        int dk = idx >> 3;
        int ss = (idx & 7) * 8;
        unsigned short pk[8];
        for (int j = 0; j < 8; j++) pk[j] = T[ss + j][dk];
        *(uint4*)&Vt[((long)(b * H_ + h) * DK_ + dk) * S_ + s0 + ss] = *(uint4*)pk;
    }
}

// ---------------------------------------------------------------------------
// Causal flash attention: paired q-strips (qa, qb=31-qa), LDS-staged K/V
// double-buffered via async16, one barrier per kv tile, transposed dataflow.
// FIXED-MAX softmax: scores (exp2 domain, Q pre-scaled by 0.125*log2e) are
// bounded by |q||k|/8*log2e <= 11.6 since RMSNorm gives ||row||=8; p =
// exp2(s - 13) never overflows and softmax is shift-invariant -> no running
// max, no alpha rescale, row-sum accumulated in-register and reduced ONCE
// after the loop.
// ---------------------------------------------------------------------------
__global__ __launch_bounds__(256, 2) void attn_kernel(
    const unsigned short* __restrict__ Q,   // (B*H, S, DK) bf16, pre-scaled
    const unsigned short* __restrict__ K,   // (B*H, S, DK) bf16
    const unsigned short* __restrict__ Vt,  // (B*H, DK, S) bf16
    unsigned short* __restrict__ O)         // (B, S, D) bf16
{
    __shared__ unsigned short Kbuf[2][64 * 64];
    __shared__ unsigned short Vbuf[2][64 * 64];
    __shared__ unsigned short Pscr[4][2][16 * 72];

    const int tid  = threadIdx.x;
    const int wave = tid >> 6;
    const int lane = tid & 63;
    const int l15  = lane & 15;
    const int quad = lane >> 4;
    const int qa   = blockIdx.x;          // 0..15
    const int qb   = 31 - qa;             // 16..31
    const int bh   = blockIdx.y;
    const int b    = bh >> 4;
    const int h    = bh & 15;
    const long baseQ = (long)bh * S_ * DK_;
    const long baseV = (long)bh * DK_ * S_;
    const float FM = 13.0f;

    const int rowc  = lane >> 3;
    const int slotS = ((lane & 7) ^ rowc) * 8;
    const int cA    = wave * 2, cB = wave * 2 + 1;

    const unsigned short* gK0 = K  + baseQ + (long)(cA * 8 + rowc) * DK_ + slotS;
    const unsigned short* gK1 = K  + baseQ + (long)(cB * 8 + rowc) * DK_ + slotS;
    const unsigned short* gV0 = Vt + baseV + (long)(cA * 8 + rowc) * S_ + slotS;
    const unsigned short* gV1 = Vt + baseV + (long)(cB * 8 + rowc) * S_ + slotS;
    const int ldsOffA = cA * 512 + lane * 8;
    const int ldsOffB = cB * 512 + lane * 8;

    vshort8 bqA[2], bqB[2];
    {
        int qA = qa * 64 + wave * 16 + l15;
        int qB = qb * 64 + wave * 16 + l15;
        for (int kh = 0; kh < 2; kh++) {
            bqA[kh] = *(const vshort8*)&Q[baseQ + (long)qA * DK_ + kh * 32 + quad * 8];
            bqB[kh] = *(const vshort8*)&Q[baseQ + (long)qB * DK_ + kh * 32 + quad * 8];
        }
    }

    vfloat4 OaccA[4], OaccB[4];
    for (int dt = 0; dt < 4; dt++) {
        vfloat4 zz = {0.f, 0.f, 0.f, 0.f};
        OaccA[dt] = zz; OaccB[dt] = zz;
    }
    float rsA = 0.f, rsB = 0.f;

    unsigned short* PA = &Pscr[wave][0][0];
    unsigned short* PB = &Pscr[wave][1][0];

    const int nkt = qb + 1;

    async16(gK0, &Kbuf[0][ldsOffA]);
    async16(gK1, &Kbuf[0][ldsOffB]);
    async16(gV0, &Vbuf[0][ldsOffA]);
    async16(gV1, &Vbuf[0][ldsOffB]);
    __syncthreads();

    for (int t = 0; t < nkt; t++) {
        const int cur = t & 1;
        if (t + 1 < nkt) {
            const int nxt = cur ^ 1;
            const long ko = (long)(t + 1) * 64;
            async16(gK0 + ko * DK_, &Kbuf[nxt][ldsOffA]);
            async16(gK1 + ko * DK_, &Kbuf[nxt][ldsOffB]);
            async16(gV0 + ko,       &Vbuf[nxt][ldsOffA]);
            async16(gV1 + ko,       &Vbuf[nxt][ldsOffB]);
        }

        vshort8 ak[4][2];
        for (int ct = 0; ct < 4; ct++)
            for (int kh = 0; kh < 2; kh++) {
                int r = ct * 16 + l15;
                int sl = (kh * 4 + quad) ^ (l15 & 7);
                ak[ct][kh] = *(const vshort8*)&Kbuf[cur][r * 64 + sl * 8];
            }
        vshort8 av[4][2];
        for (int dt = 0; dt < 4; dt++)
            for (int kh = 0; kh < 2; kh++) {
                int r = dt * 16 + l15;
                int sl = (kh * 4 + quad) ^ (l15 & 7);
                av[dt][kh] = *(const vshort8*)&Vbuf[cur][r * 64 + sl * 8];
            }

        const int k0 = t * 64;
        const bool actA = (t <= qa);

        if (actA) {   // ---- strip A ----
            vfloat4 sc[4];
            for (int ct = 0; ct < 4; ct++) {
                vfloat4 a = {0.f, 0.f, 0.f, 0.f};
                a = __builtin_amdgcn_mfma_f32_16x16x32_bf16(ak[ct][0], bqA[0], a, 0, 0, 0);
                a = __builtin_amdgcn_mfma_f32_16x16x32_bf16(ak[ct][1], bqA[1], a, 0, 0, 0);
                sc[ct] = a;
            }
            if (t == qa) {
                int qg = qa * 64 + wave * 16 + l15;
                for (int ct = 0; ct < 4; ct++) {
                    int kvb = k0 + ct * 16 + quad * 4;
                    for (int r = 0; r < 4; r++)
                        if (kvb + r > qg) sc[ct][r] = -1e30f;
                }
            }
            for (int ct = 0; ct < 4; ct++) {
                float p0 = exp2f(sc[ct][0] - FM);
                float p1 = exp2f(sc[ct][1] - FM);
                float p2 = exp2f(sc[ct][2] - FM);
                float p3 = exp2f(sc[ct][3] - FM);
                rsA += (p0 + p1) + (p2 + p3);
                uint2 o;
                o.x = (unsigned int)f2bf_fast(p0) | ((unsigned int)f2bf_fast(p1) << 16);
                o.y = (unsigned int)f2bf_fast(p2) | ((unsigned int)f2bf_fast(p3) << 16);
                *(uint2*)&PA[l15 * 72 + ct * 16 + quad * 4] = o;
            }
            vshort8 bp[2];
            for (int kh = 0; kh < 2; kh++)
                bp[kh] = *(const vshort8*)&PA[l15 * 72 + kh * 32 + quad * 8];
            for (int dt = 0; dt < 4; dt++) {
                OaccA[dt] = __builtin_amdgcn_mfma_f32_16x16x32_bf16(av[dt][0], bp[0], OaccA[dt], 0, 0, 0);
                OaccA[dt] = __builtin_amdgcn_mfma_f32_16x16x32_bf16(av[dt][1], bp[1], OaccA[dt], 0, 0, 0);
            }
        }

        {   // ---- strip B (always active) ----
            vfloat4 sc[4];
            for (int ct = 0; ct < 4; ct++) {
                vfloat4 a = {0.f, 0.f, 0.f, 0.f};
                a = __builtin_amdgcn_mfma_f32_16x16x32_bf16(ak[ct][0], bqB[0], a, 0, 0, 0);
                a = __builtin_amdgcn_mfma_f32_16x16x32_bf16(ak[ct][1], bqB[1], a, 0, 0, 0);
                sc[ct] = a;
            }
            if (t == nkt - 1) {
                int qg = qb * 64 + wave * 16 + l15;
                for (int ct = 0; ct < 4; ct++) {
                    int kvb = k0 + ct * 16 + quad * 4;
                    for (int r = 0; r < 4; r++)
                        if (kvb + r > qg) sc[ct][r] = -1e30f;
                }
            }
            for (int ct = 0; ct < 4; ct++) {
                float p0 = exp2f(sc[ct][0] - FM);
                float p1 = exp2f(sc[ct][1] - FM);
                float p2 = exp2f(sc[ct][2] - FM);
                float p3 = exp2f(sc[ct][3] - FM);
                rsB += (p0 + p1) + (p2 + p3);
                uint2 o;
                o.x = (unsigned int)f2bf_fast(p0) | ((unsigned int)f2bf_fast(p1) << 16);
                o.y = (unsigned int)f2bf_fast(p2) | ((unsigned int)f2bf_fast(p3) << 16);
                *(uint2*)&PB[l15 * 72 + ct * 16 + quad * 4] = o;
            }
            vshort8 bp[2];
            for (int kh = 0; kh < 2; kh++)
                bp[kh] = *(const vshort8*)&PB[l15 * 72 + kh * 32 + quad * 8];
            for (int dt = 0; dt < 4; dt++) {
                OaccB[dt] = __builtin_amdgcn_mfma_f32_16x16x32_bf16(av[dt][0], bp[0], OaccB[dt], 0, 0, 0);
                OaccB[dt] = __builtin_amdgcn_mfma_f32_16x16x32_bf16(av[dt][1], bp[1], OaccB[dt], 0, 0, 0);
            }
        }

        __syncthreads();   // all waves done with buf[cur]; prefetch drained
    }

    // single row-sum reduce per strip (quads hold disjoint kv subsets)
    rsA += __shfl_xor(rsA, 16, 64);
    rsA += __shfl_xor(rsA, 32, 64);
    rsB += __shfl_xor(rsB, 16, 64);
    rsB += __shfl_xor(rsB, 32, 64);

    {
        float inv = 1.0f / rsA;
        int qg = qa * 64 + wave * 16 + l15;
        long rowbase = (long)(b * S_ + qg) * D_ + h * 64;
        for (int dt = 0; dt < 4; dt++) {
            unsigned short pk[4];
            for (int r = 0; r < 4; r++) pk[r] = f2bf(OaccA[dt][r] * inv);
            uint2 o;
            o.x = (unsigned int)pk[0] | ((unsigned int)pk[1] << 16);
            o.y = (unsigned int)pk[2] | ((unsigned int)pk[3] << 16);
            *(uint2*)&O[rowbase + dt * 16 + quad * 4] = o;
        }
    }
    {
        float inv = 1.0f / rsB;
        int qg = qb * 64 + wave * 16 + l15;
        long rowbase = (long)(b * S_ + qg) * D_ + h * 64;
        for (int dt = 0; dt < 4; dt++) {
            unsigned short pk[4];
            for (int r = 0; r < 4; r++) pk[r] = f2bf(OaccB[dt][r] * inv);
            uint2 o;
            o.x = (unsigned int)pk[0] | ((unsigned int)pk[1] << 16);
            o.y = (unsigned int)pk[2] | ((unsigned int)pk[3] << 16);
            *(uint2*)&O[rowbase + dt * 16 + quad * 4] = o;
        }
    }
}

// ---------------------------------------------------------------------------
extern "C" void kernel_launch(void* const* d_in, const int* in_sizes, int n_in,
                              void* d_out, int out_size, void* d_ws, size_t ws_size,
                              hipStream_t stream) {
    const float* q    = (const float*)d_in[0];
    const float* k    = (const float*)d_in[1];
    const float* v    = (const float*)d_in[2];
    const float* cosb = (const float*)d_in[4];
    const float* sinb = (const float*)d_in[5];
    const float* wq   = (const float*)d_in[6];
    const float* bq   = (const float*)d_in[7];
    const float* wk   = (const float*)d_in[8];
    const float* bk   = (const float*)d_in[9];
    const float* wv   = (const float*)d_in[10];
    const float* bv   = (const float*)d_in[11];
    const float* wo   = (const float*)d_in[12];
    const float* bo   = (const float*)d_in[13];
    const float* qn_w = (const float*)d_in[14];
    const float* kn_w = (const float*)d_in[15];

    const long MB = 1024 * 1024;
    char* ws = (char*)d_ws;
    // xq 0-8, xk 8-16, xv 16-24, weights 24-32,
    // Qn 32-40, Kn 40-48, tmpv 48-56, Vtb 56-64, Ob 64-72   (72 MB total)
    unsigned short* xq   = (unsigned short*)(ws + 0 * MB);
    unsigned short* xk   = (unsigned short*)(ws + 8 * MB);
    unsigned short* xv   = (unsigned short*)(ws + 16 * MB);
    unsigned short* wqb  = (unsigned short*)(ws + 24 * MB);
    unsigned short* wkb  = (unsigned short*)(ws + 26 * MB);
    unsigned short* wvb  = (unsigned short*)(ws + 28 * MB);
    unsigned short* wob  = (unsigned short*)(ws + 30 * MB);
    unsigned short* Qn   = (unsigned short*)(ws + 32 * MB);
    unsigned short* Kn   = (unsigned short*)(ws + 40 * MB);
    unsigned short* tmpv = (unsigned short*)(ws + 48 * MB);
    unsigned short* Vtb  = (unsigned short*)(ws + 56 * MB);
    unsigned short* Ob   = (unsigned short*)(ws + 64 * MB);

    dim3 blk(256);
    cast_bf16_kernel<<<dim3(2048, 1, 3), blk, 0, stream>>>(q, k, v, q, xq, xk, xv, xq);
    cast_bf16_kernel<<<dim3(512, 1, 4), blk, 0, stream>>>(wq, wk, wv, wo, wqb, wkb, wvb, wob);

    // fused QKV projection + normrope epilogue (768 blocks = 3 blocks/CU)
    gemm_bt_kernel<<<dim3(8, 32, 3), blk, 0, stream>>>(
        xq, xk, xv, wqb, wkb, wvb, bq, bk, bv,
        Qn, Kn, tmpv, nullptr, qn_w, kn_w, cosb, sinb, 1);

    transpose_v_kernel<<<dim3(32, 32), blk, 0, stream>>>(tmpv, Vtb);

    attn_kernel<<<dim3(16, 32), blk, 0, stream>>>(Qn, Kn, Vtb, Ob);

    // output projection, f32 out
    gemm_bt_kernel<<<dim3(8, 32, 1), blk, 0, stream>>>(
        Ob, Ob, Ob, wob, wob, wob, bo, bo, bo,
        nullptr, nullptr, nullptr, (float*)d_out, nullptr, nullptr, nullptr, nullptr, 0);
}